// Round 4
// baseline (220.393 us; speedup 1.0000x reference)
//
#include <hip/hip_runtime.h>
#include <hip/hip_bf16.h>

#define B_DIM 64
#define T_DIM 512
#define H_DIM 1024

typedef __attribute__((ext_vector_type(8))) __bf16 bf16x8;
typedef __attribute__((ext_vector_type(8))) unsigned short u16x8;
typedef __attribute__((ext_vector_type(16))) float f32x16;

// ws layout (bytes)
#define PREVBF_OFF 0UL            // A' frag-major: 64*512*1024*2 = 67108864
#define WBF_OFF    67108864UL     // B' frag-major: 1024*1024*2   =  2097152
#define DEC_OFF    69206016UL     // 64*1024*4     =   262144
#define PART_OFF   69468160UL     // 32768*8*4     =  1048576
#define AT_OFF     70516736UL     // 32768*4       =   131072
// total 70647808 bytes

__device__ __forceinline__ unsigned short f2bf(float x) {
  unsigned u = __float_as_uint(x);
  unsigned r = (u + 0x7FFFu + ((u >> 16) & 1u)) >> 16;  // RNE
  return (unsigned short)r;
}
__device__ __forceinline__ float bf2f(unsigned short u) {
  return __uint_as_float(((unsigned)u) << 16);
}

__device__ __forceinline__ void gload_lds16(const void* g, void* l) {
  __builtin_amdgcn_global_load_lds(
      (const __attribute__((address_space(1))) void*)g,
      (__attribute__((address_space(3))) void*)l, 16, 0, 0);
}

// Fragment-major layout: X'[(row>>5)][(k>>4)][(k>>3)&1][row&31][k&7]
// element offset = ((row>>5)*64 + (k>>4))*512 + ((k>>3)&1)*256 + (row&31)*8 + (k&7)
// A wave-load of 512 consecutive ushorts (lane*8) = one 32x16 MFMA operand frag.

// K1: prep — convert prev_s -> A' (+ fp32 concat copy), W_prev -> B', s_t -> out tail.
__global__ void prep_ws(const float* __restrict__ prev,
                        const float* __restrict__ st,
                        const float* __restrict__ Wp,
                        float* __restrict__ out,
                        unsigned short* __restrict__ Aq,
                        unsigned short* __restrict__ Bq) {
  int wid = blockIdx.x * 4 + (threadIdx.x >> 6);
  int lane = threadIdx.x & 63;
  int hi = lane >> 5, r = lane & 31;
  if (wid < 8192) {
    // A-task: m-tile = wid>>3 (32 rows), kg range = (wid&7)*8 .. +8
    int mt = wid >> 3;
    int kg0 = (wid & 7) * 8;
    int m = mt * 32 + r;
    int b = m >> 9, t = m & 511;
    const float* src = prev + (size_t)m * 1024;
    float* outp = out + 65536 + (size_t)b * 525312 + (size_t)t * 1024;
    #pragma unroll
    for (int kg = kg0; kg < kg0 + 8; kg++) {
      int k0 = kg * 16 + hi * 8;
      float4 f0 = *(const float4*)(src + k0);
      float4 f1 = *(const float4*)(src + k0 + 4);
      *(float4*)(outp + k0) = f0;
      *(float4*)(outp + k0 + 4) = f1;
      u16x8 u;
      u[0] = f2bf(f0.x); u[1] = f2bf(f0.y); u[2] = f2bf(f0.z); u[3] = f2bf(f0.w);
      u[4] = f2bf(f1.x); u[5] = f2bf(f1.y); u[6] = f2bf(f1.z); u[7] = f2bf(f1.w);
      *(u16x8*)(Aq + ((size_t)mt * 64 + kg) * 512 + (size_t)lane * 8) = u;
    }
  } else if (wid < 8448) {
    // B-task: n-tile = rel>>3, kg range
    int rel = wid - 8192;
    int nt = rel >> 3;
    int kg0 = (rel & 7) * 8;
    int n = nt * 32 + r;
    const float* src = Wp + (size_t)n * 1024;
    #pragma unroll
    for (int kg = kg0; kg < kg0 + 8; kg++) {
      int k0 = kg * 16 + hi * 8;
      float4 f0 = *(const float4*)(src + k0);
      float4 f1 = *(const float4*)(src + k0 + 4);
      u16x8 u;
      u[0] = f2bf(f0.x); u[1] = f2bf(f0.y); u[2] = f2bf(f0.z); u[3] = f2bf(f0.w);
      u[4] = f2bf(f1.x); u[5] = f2bf(f1.y); u[6] = f2bf(f1.z); u[7] = f2bf(f1.w);
      *(u16x8*)(Bq + ((size_t)nt * 64 + kg) * 512 + (size_t)lane * 8) = u;
    }
  } else if (wid < 8512) {
    // s_t copy into concat tail row
    int b = wid - 8448;
    const float4* s4 = (const float4*)st;
    float4* o4 = (float4*)(out + 65536 + (size_t)b * 525312 + 524288);
    #pragma unroll
    for (int i = 0; i < 4; i++)
      o4[i * 64 + lane] = s4[(size_t)b * 256 + i * 64 + lane];
  }
}

// K2: dec_fea[b][o] = sum_h s_t[b][h]*W_s[o][h] + b_s[o]
__global__ void dec_kernel(const float* __restrict__ st,
                           const float* __restrict__ Ws,
                           const float* __restrict__ bs,
                           float* __restrict__ dec) {
  int tid = threadIdx.x;
  int lane = tid & 63, w = tid >> 6;
  int o = blockIdx.x * 4 + w;
  const float4* wrow = (const float4*)(Ws + (size_t)o * H_DIM);
  float4 w0 = wrow[lane], w1 = wrow[64 + lane], w2 = wrow[128 + lane], w3 = wrow[192 + lane];
  const float4* st4 = (const float4*)st;
  float bias = bs[o];
  #pragma unroll 8
  for (int b = 0; b < B_DIM; b++) {
    const float4* s = st4 + (size_t)b * 256;
    float4 s0 = s[lane], s1 = s[64 + lane], s2 = s[128 + lane], s3 = s[192 + lane];
    float p = w0.x * s0.x + w0.y * s0.y + w0.z * s0.z + w0.w * s0.w
            + w1.x * s1.x + w1.y * s1.y + w1.z * s1.z + w1.w * s1.w
            + w2.x * s2.x + w2.y * s2.y + w2.z * s2.z + w2.w * s2.w
            + w3.x * s3.x + w3.y * s3.y + w3.z * s3.z + w3.w * s3.w;
    p += __shfl_xor(p, 1);  p += __shfl_xor(p, 2);
    p += __shfl_xor(p, 4);  p += __shfl_xor(p, 8);
    p += __shfl_xor(p, 16); p += __shfl_xor(p, 32);
    if (lane == 0) dec[(size_t)b * H_DIM + o] = p + bias;
  }
}

// K3: weights-stationary score GEMM, barrier-free K-loop.
// Block: 512 thr = 8 waves (8M x 1N). Block tile 512 rows x 128 cols.
// B' (128 cols x 1024 K) lives in LDS as double-buffered 256-K quarters.
// A-frags are direct coalesced global loads (fragment-major A').
__global__ __launch_bounds__(512, 2) void score_ws(
    const unsigned short* __restrict__ Aq,
    const unsigned short* __restrict__ Bq,
    const float* __restrict__ dec,
    const float* __restrict__ v,
    float* __restrict__ part)
{
  __shared__ __align__(16) unsigned short lds[2][32768];  // 2 x 64KB

  int orig = blockIdx.x;                    // 512 blocks
  int swz = (orig & 7) * 64 + (orig >> 3);  // bijective XCD swizzle
  int bm = swz >> 3, bn = swz & 7;          // 64 m-blocks x 8 n-blocks

  int tid = threadIdx.x, lane = tid & 63, wm = tid >> 6;
  size_t m0 = (size_t)bm * 512;
  int n0 = bn * 128;

  // A frag base for this wave: MT0 = bm*16 + wm*2 ; A(mf,kgg) = +mf*32768 + kgg*512
  const unsigned short* Abase = Aq + ((size_t)bm * 16 + wm * 2) * 64 * 512 + (size_t)lane * 8;

  f32x16 acc[2][4];
  #pragma unroll
  for (int i = 0; i < 2; i++)
    #pragma unroll
    for (int j = 0; j < 4; j++)
      #pragma unroll
      for (int e = 0; e < 16; e++) acc[i][j][e] = 0.f;

  // stage one 256-K quarter of B' (64KB = 4096 chunks; 8 per thread)
  auto stageQ = [&](int q, int buf) {
    #pragma unroll
    for (int i = 0; i < 8; i++) {
      int c = tid + i * 512;
      int nt = c >> 10, rest = c & 1023;
      const unsigned short* src = Bq + ((size_t)(bn * 4 + nt) * 64 + q * 16) * 512 + (size_t)rest * 8;
      gload_lds16(src, (char*)&lds[buf][0] + (size_t)c * 16);
    }
    __builtin_amdgcn_sched_barrier(0);
  };

  bf16x8 cA0, cA1, pA0, pA1, nA0, nA1;
  bf16x8 cB0, cB1, cB2, cB3, nB0, nB1, nB2, nB3;

  stageQ(0, 0);
  pA0 = *(const bf16x8*)(Abase);
  pA1 = *(const bf16x8*)(Abase + 32768);
  nA0 = *(const bf16x8*)(Abase + 512);
  nA1 = *(const bf16x8*)(Abase + 32768 + 512);
  asm volatile("s_waitcnt vmcnt(4)" ::: "memory");  // stage done; A prefetches may fly
  __builtin_amdgcn_s_barrier();
  nB0 = *(const bf16x8*)&lds[0][0 * 8192 + (size_t)lane * 8];
  nB1 = *(const bf16x8*)&lds[0][1 * 8192 + (size_t)lane * 8];
  nB2 = *(const bf16x8*)&lds[0][2 * 8192 + (size_t)lane * 8];
  nB3 = *(const bf16x8*)&lds[0][3 * 8192 + (size_t)lane * 8];

  #pragma unroll
  for (int q = 0; q < 4; q++) {
    int buf = q & 1;
    if (q < 3) stageQ(q + 1, buf ^ 1);
    #pragma unroll
    for (int kg = 0; kg < 16; kg++) {
      int kgg = q * 16 + kg;
      cA0 = pA0; cA1 = pA1; pA0 = nA0; pA1 = nA1;
      cB0 = nB0; cB1 = nB1; cB2 = nB2; cB3 = nB3;
      if (kgg < 62) {  // A prefetch distance 2 (address is buffer-independent)
        nA0 = *(const bf16x8*)(Abase + (size_t)(kgg + 2) * 512);
        nA1 = *(const bf16x8*)(Abase + 32768 + (size_t)(kgg + 2) * 512);
      }
      if (kg < 15) {   // B prefetch distance 1, within-quarter only
        const unsigned short* bb = &lds[buf][(size_t)(kg + 1) * 512 + (size_t)lane * 8];
        nB0 = *(const bf16x8*)(bb + 0 * 8192);
        nB1 = *(const bf16x8*)(bb + 1 * 8192);
        nB2 = *(const bf16x8*)(bb + 2 * 8192);
        nB3 = *(const bf16x8*)(bb + 3 * 8192);
      }
      acc[0][0] = __builtin_amdgcn_mfma_f32_32x32x16_bf16(cA0, cB0, acc[0][0], 0, 0, 0);
      acc[0][1] = __builtin_amdgcn_mfma_f32_32x32x16_bf16(cA0, cB1, acc[0][1], 0, 0, 0);
      acc[0][2] = __builtin_amdgcn_mfma_f32_32x32x16_bf16(cA0, cB2, acc[0][2], 0, 0, 0);
      acc[0][3] = __builtin_amdgcn_mfma_f32_32x32x16_bf16(cA0, cB3, acc[0][3], 0, 0, 0);
      acc[1][0] = __builtin_amdgcn_mfma_f32_32x32x16_bf16(cA1, cB0, acc[1][0], 0, 0, 0);
      acc[1][1] = __builtin_amdgcn_mfma_f32_32x32x16_bf16(cA1, cB1, acc[1][1], 0, 0, 0);
      acc[1][2] = __builtin_amdgcn_mfma_f32_32x32x16_bf16(cA1, cB2, acc[1][2], 0, 0, 0);
      acc[1][3] = __builtin_amdgcn_mfma_f32_32x32x16_bf16(cA1, cB3, acc[1][3], 0, 0, 0);
    }
    if (q < 3) {
      // ledger: 8 stage loads (oldest) + 4 in-flight A prefetches (newest)
      asm volatile("s_waitcnt vmcnt(4)" ::: "memory");
      __builtin_amdgcn_s_barrier();
      const unsigned short* bb = &lds[buf ^ 1][(size_t)lane * 8];
      nB0 = *(const bf16x8*)(bb + 0 * 8192);
      nB1 = *(const bf16x8*)(bb + 1 * 8192);
      nB2 = *(const bf16x8*)(bb + 2 * 8192);
      nB3 = *(const bf16x8*)(bb + 3 * 8192);
    }
  }

  // epilogue: tanh + dot v; reduce over the 128 cols of this n-block.
  // C layout (32x32): col = lane&31, row = (r&3) + 8*(r>>2) + 4*(lane>>5)
  int b = bm;  // block spans exactly one batch (512 rows)
  int cl = lane & 31, hi = lane >> 5;
  float dv[4], vv[4];
  #pragma unroll
  for (int nf = 0; nf < 4; nf++) {
    int col = n0 + nf * 32 + cl;
    dv[nf] = dec[(size_t)b * H_DIM + col];
    vv[nf] = v[col];
  }
  #pragma unroll
  for (int mf = 0; mf < 2; mf++) {
    #pragma unroll
    for (int r = 0; r < 16; r++) {
      float s = 0.f;
      #pragma unroll
      for (int nf = 0; nf < 4; nf++) {
        float x = acc[mf][nf][r] + dv[nf];
        x = fminf(fmaxf(x, -15.f), 15.f);
        float e = __expf(2.f * x);
        s += vv[nf] * (e - 1.f) * __builtin_amdgcn_rcpf(e + 1.f);
      }
      s += __shfl_xor(s, 1); s += __shfl_xor(s, 2);
      s += __shfl_xor(s, 4); s += __shfl_xor(s, 8); s += __shfl_xor(s, 16);
      if (cl == 0) {
        size_t row = m0 + wm * 64 + mf * 32 + (r & 3) + 8 * (r >> 2) + 4 * hi;
        part[row * 8 + bn] = s;
      }
    }
  }
}

// K4: softmax over T per batch row (8 partials per row)
__global__ void softmax_kernel(const float* __restrict__ part, float* __restrict__ at) {
  int b = blockIdx.x, tid = threadIdx.x;
  __shared__ float sc[512];
  __shared__ float red[8];
  #pragma unroll
  for (int rep = 0; rep < 2; rep++) {
    int t = rep * 256 + tid;
    const float* p = part + ((size_t)b * 512 + t) * 8;
    sc[t] = p[0] + p[1] + p[2] + p[3] + p[4] + p[5] + p[6] + p[7];
  }
  __syncthreads();
  float m = fmaxf(sc[tid], sc[tid + 256]);
  for (int d = 1; d < 64; d <<= 1) m = fmaxf(m, __shfl_xor(m, d));
  if ((tid & 63) == 0) red[tid >> 6] = m;
  __syncthreads();
  m = fmaxf(fmaxf(red[0], red[1]), fmaxf(red[2], red[3]));
  float e0 = __expf(sc[tid] - m), e1 = __expf(sc[tid + 256] - m);
  float s = e0 + e1;
  for (int d = 1; d < 64; d <<= 1) s += __shfl_xor(s, d);
  if ((tid & 63) == 0) red[4 + (tid >> 6)] = s;
  __syncthreads();
  s = red[4] + red[5] + red[6] + red[7];
  float inv = 1.f / s;
  at[(size_t)b * 512 + tid] = e0 * inv;
  at[(size_t)b * 512 + tid + 256] = e1 * inv;
}

// K5: ct_d[b][h] = sum_t at[b][t]*prev[b][t][h], reading fragment-major A'.
// One wave owns (b, kg): 16 h-values, full t-reduction in-wave. No atomics.
__global__ void ctd_ws(const unsigned short* __restrict__ Aq,
                       const float* __restrict__ at, float* __restrict__ out) {
  int wid = blockIdx.x * 4 + (threadIdx.x >> 6);  // 4096 = 64 b x 64 kg
  int lane = threadIdx.x & 63;
  int b = wid >> 6, kg = wid & 63;
  int hi = lane >> 5, r = lane & 31;
  float a8[8] = {0.f, 0.f, 0.f, 0.f, 0.f, 0.f, 0.f, 0.f};
  const unsigned short* base = Aq + ((size_t)b * 16 * 64 + kg) * 512 + (size_t)lane * 8;
  const float* atb = at + (size_t)b * 512 + r;
  #pragma unroll
  for (int mt = 0; mt < 16; mt++) {
    float a = atb[mt * 32];
    u16x8 val = *(const u16x8*)(base + (size_t)mt * 32768);
    #pragma unroll
    for (int j = 0; j < 8; j++) a8[j] += a * bf2f(val[j]);
  }
  #pragma unroll
  for (int d = 1; d < 32; d <<= 1)
    #pragma unroll
    for (int j = 0; j < 8; j++) a8[j] += __shfl_xor(a8[j], d);
  if (r == 0) {
    #pragma unroll
    for (int j = 0; j < 8; j++)
      out[(size_t)b * H_DIM + kg * 16 + hi * 8 + j] = a8[j];
  }
}

extern "C" void kernel_launch(void* const* d_in, const int* in_sizes, int n_in,
                              void* d_out, int out_size, void* d_ws, size_t ws_size,
                              hipStream_t stream) {
  (void)in_sizes; (void)n_in; (void)out_size; (void)ws_size;
  const float* s_t    = (const float*)d_in[0];
  const float* prev_s = (const float*)d_in[1];
  const float* W_prev = (const float*)d_in[2];
  const float* W_s    = (const float*)d_in[3];
  const float* b_s    = (const float*)d_in[4];
  const float* v      = (const float*)d_in[5];
  float* out = (float*)d_out;
  char* ws = (char*)d_ws;

  unsigned short* Aq  = (unsigned short*)(ws + PREVBF_OFF);
  unsigned short* Bq  = (unsigned short*)(ws + WBF_OFF);
  float* dec  = (float*)(ws + DEC_OFF);
  float* part = (float*)(ws + PART_OFF);
  float* at   = (float*)(ws + AT_OFF);

  prep_ws<<<2128, 256, 0, stream>>>(prev_s, s_t, W_prev, out, Aq, Bq);
  dec_kernel<<<256, 256, 0, stream>>>(s_t, W_s, b_s, dec);
  score_ws<<<512, 512, 0, stream>>>(Aq, Bq, dec, v, part);
  softmax_kernel<<<64, 256, 0, stream>>>(part, at);
  ctd_ws<<<1024, 256, 0, stream>>>(Aq, at, out);
}

// Round 5
// 199.245 us; speedup vs baseline: 1.1061x; 1.1061x over previous
//
#include <hip/hip_runtime.h>
#include <hip/hip_bf16.h>

#define B_DIM 64
#define T_DIM 512
#define H_DIM 1024

typedef __attribute__((ext_vector_type(8))) __bf16 bf16x8;
typedef __attribute__((ext_vector_type(4))) float f32x4;

// ws layout (bytes)
#define PREVBF_OFF 0UL            // 64*512*1024*2 = 67108864
#define WBF_OFF    67108864UL     // 1024*1024*2   =  2097152
#define DEC_OFF    69206016UL     // 64*1024*4     =   262144
#define PART_OFF   69468160UL     // 32768*8*4     =  1048576
#define AT_OFF     70516736UL     // 32768*4       =   131072
// total 70647808 bytes

__device__ __forceinline__ unsigned short f2bf(float x) {
  unsigned u = __float_as_uint(x);
  unsigned r = (u + 0x7FFFu + ((u >> 16) & 1u)) >> 16;  // RNE
  return (unsigned short)r;
}
__device__ __forceinline__ float bf2f(unsigned short u) {
  return __uint_as_float(((unsigned)u) << 16);
}

__device__ __forceinline__ void gload_lds16(const void* g, void* l) {
  __builtin_amdgcn_global_load_lds(
      (const __attribute__((address_space(1))) void*)g,
      (__attribute__((address_space(3))) void*)l, 16, 0, 0);
}

// K1: copy prev_s -> out (concat region), convert prev_s -> bf16 ws,
//     copy s_t -> out tail row, convert W_prev -> bf16 ws.
__global__ void prep_kernel(const float* __restrict__ prev,
                            const float* __restrict__ st,
                            const float* __restrict__ Wp,
                            float* __restrict__ out,
                            unsigned short* __restrict__ prevbf,
                            unsigned short* __restrict__ wbf) {
  const long P4 = (long)B_DIM * T_DIM * H_DIM / 4;  // 8388608
  const long S4 = (long)B_DIM * H_DIM / 4;          // 16384
  const long W4 = (long)H_DIM * H_DIM / 4;          // 262144
  const long total = P4 + S4 + W4;
  long stride = (long)gridDim.x * blockDim.x;
  for (long i = (long)blockIdx.x * blockDim.x + threadIdx.x; i < total; i += stride) {
    if (i < P4) {
      float4 f = ((const float4*)prev)[i];
      long elem = i * 4;
      int b = (int)(elem >> 19);               // /(T*H)
      long rem = elem & ((1L << 19) - 1);
      ((float4*)out)[16384 + (long)b * 131328 + (rem >> 2)] = f;
      ushort4 u;
      u.x = f2bf(f.x); u.y = f2bf(f.y); u.z = f2bf(f.z); u.w = f2bf(f.w);
      ((ushort4*)prevbf)[i] = u;
    } else if (i < P4 + S4) {
      long j = i - P4;
      float4 f = ((const float4*)st)[j];
      long elem = j * 4;
      int b = (int)(elem >> 10);
      int h = (int)(elem & 1023);
      ((float4*)out)[16384 + (long)b * 131328 + 131072 + (h >> 2)] = f;
    } else {
      long j = i - P4 - S4;
      float4 f = ((const float4*)Wp)[j];
      ushort4 u;
      u.x = f2bf(f.x); u.y = f2bf(f.y); u.z = f2bf(f.z); u.w = f2bf(f.w);
      ((ushort4*)wbf)[j] = u;
    }
  }
}

// K2: dec_fea[b][o] = sum_h s_t[b][h]*W_s[o][h] + b_s[o]
__global__ void dec_kernel(const float* __restrict__ st,
                           const float* __restrict__ Ws,
                           const float* __restrict__ bs,
                           float* __restrict__ dec) {
  int tid = threadIdx.x;
  int lane = tid & 63, w = tid >> 6;
  int o = blockIdx.x * 4 + w;
  const float4* wrow = (const float4*)(Ws + (size_t)o * H_DIM);
  float4 w0 = wrow[lane], w1 = wrow[64 + lane], w2 = wrow[128 + lane], w3 = wrow[192 + lane];
  const float4* st4 = (const float4*)st;
  float bias = bs[o];
  #pragma unroll 8
  for (int b = 0; b < B_DIM; b++) {
    const float4* s = st4 + (size_t)b * 256;
    float4 s0 = s[lane], s1 = s[64 + lane], s2 = s[128 + lane], s3 = s[192 + lane];
    float p = w0.x * s0.x + w0.y * s0.y + w0.z * s0.z + w0.w * s0.w
            + w1.x * s1.x + w1.y * s1.y + w1.z * s1.z + w1.w * s1.w
            + w2.x * s2.x + w2.y * s2.y + w2.z * s2.z + w2.w * s2.w
            + w3.x * s3.x + w3.y * s3.y + w3.z * s3.z + w3.w * s3.w;
    p += __shfl_xor(p, 1);  p += __shfl_xor(p, 2);
    p += __shfl_xor(p, 4);  p += __shfl_xor(p, 8);
    p += __shfl_xor(p, 16); p += __shfl_xor(p, 32);
    if (lane == 0) dec[(size_t)b * H_DIM + o] = p + bias;
  }
}

// K3: scores partials. et = A(bf16 prev_s)[M,K] x W(bf16)[N,K]^T, fused
// epilogue: part[m][bn] = sum_{o in 128-tile} tanh(et+dec)*v[o].
// 128x128 block tile, 2x2 waves of 64x64, BK=32 double-buffered LDS,
// XOR-swizzled, raw s_barrier pairs + counted vmcnt(4) (1-tile prefetch depth).
__global__ __launch_bounds__(256, 4) void score_gemm(
    const unsigned short* __restrict__ A,   // [32768][1024] bf16
    const unsigned short* __restrict__ Bw,  // [1024][1024] bf16
    const float* __restrict__ dec,          // [64][1024]
    const float* __restrict__ v,            // [1024]
    float* __restrict__ part)               // [32768][8]
{
  __shared__ __align__(16) unsigned short ldsA[2][128 * 32];
  __shared__ __align__(16) unsigned short ldsB[2][128 * 32];

  int orig = blockIdx.x;                       // 2048 blocks
  int swz = (orig & 7) * 256 + (orig >> 3);    // bijective XCD swizzle
  int bm = swz >> 3, bn = swz & 7;

  int tid = threadIdx.x;
  int lane = tid & 63, w = tid >> 6;
  int wm = w >> 1, wn = w & 1;                 // 2x2 waves, 64x64 each
  size_t m0 = (size_t)bm * 128;
  int n0 = bn * 128;

  f32x4 acc[4][4];
  #pragma unroll
  for (int i = 0; i < 4; i++)
    #pragma unroll
    for (int j = 0; j < 4; j++) {
      f32x4 z; z.x = 0.f; z.y = 0.f; z.z = 0.f; z.w = 0.f;
      acc[i][j] = z;
    }

  int lr = lane >> 4, lc = lane & 15;

  // staging: 512 16B-chunks per matrix per tile; 2 per thread.
  // chunk idx -> row = idx>>2, sub = idx&3; global sub' = sub ^ ((row>>1)&3)
  int sidx0 = tid, sidx1 = 256 + tid;
  int srow0 = sidx0 >> 2, ssub0 = (sidx0 & 3) ^ ((srow0 >> 1) & 3);
  int srow1 = sidx1 >> 2, ssub1 = (sidx1 & 3) ^ ((srow1 >> 1) & 3);
  const unsigned short* gA0 = A + (m0 + srow0) * 1024 + ssub0 * 8;
  const unsigned short* gA1 = A + (m0 + srow1) * 1024 + ssub1 * 8;
  const unsigned short* gB0 = Bw + (size_t)(n0 + srow0) * 1024 + ssub0 * 8;
  const unsigned short* gB1 = Bw + (size_t)(n0 + srow1) * 1024 + ssub1 * 8;

  // read offsets (ushort units): logical chunk lr stored at chunk lr^((row>>1)&3)
  int offA[4], offB[4];
  #pragma unroll
  for (int f = 0; f < 4; f++) {
    int ra = wm * 64 + f * 16 + lc;
    offA[f] = ra * 32 + ((lr ^ ((ra >> 1) & 3)) << 3);
    int rb = wn * 64 + f * 16 + lc;
    offB[f] = rb * 32 + ((lr ^ ((rb >> 1) & 3)) << 3);
  }

  // prologue: stage tile 0 into buffer 0 (4 loads/thread in flight)
  gload_lds16(gA0, &ldsA[0][sidx0 * 8]);
  gload_lds16(gA1, &ldsA[0][sidx1 * 8]);
  gload_lds16(gB0, &ldsB[0][sidx0 * 8]);
  gload_lds16(gB1, &ldsB[0][sidx1 * 8]);

  #pragma unroll 2
  for (int t = 0; t < 32; t++) {
    int cur = t & 1, nxt = cur ^ 1;
    if (t < 31) {
      int k = (t + 1) * 32;
      // buf[nxt] was read at iter t-1; its barrier2 already passed -> safe
      gload_lds16(gA0 + k, &ldsA[nxt][sidx0 * 8]);
      gload_lds16(gA1 + k, &ldsA[nxt][sidx1 * 8]);
      gload_lds16(gB0 + k, &ldsB[nxt][sidx0 * 8]);
      gload_lds16(gB1 + k, &ldsB[nxt][sidx1 * 8]);
      asm volatile("s_waitcnt vmcnt(4)" ::: "memory");  // cur landed; nxt in flight
    } else {
      asm volatile("s_waitcnt vmcnt(0)" ::: "memory");
    }
    __builtin_amdgcn_s_barrier();                       // cur visible to all waves
    asm volatile("" ::: "memory");
    bf16x8 av[4], bv[4];
    #pragma unroll
    for (int f = 0; f < 4; f++) av[f] = *(const bf16x8*)&ldsA[cur][offA[f]];
    #pragma unroll
    for (int f = 0; f < 4; f++) bv[f] = *(const bf16x8*)&ldsB[cur][offB[f]];
    #pragma unroll
    for (int mf = 0; mf < 4; mf++)
      #pragma unroll
      for (int nf = 0; nf < 4; nf++)
        acc[mf][nf] = __builtin_amdgcn_mfma_f32_16x16x32_bf16(av[mf], bv[nf], acc[mf][nf], 0, 0, 0);
    asm volatile("" ::: "memory");
    __builtin_amdgcn_s_barrier();                       // all reads of cur retired
  }

  // epilogue: tanh + dot v over this wave's 64 cols; 2-way wn-reduce via LDS
  int b = (int)(m0 >> 9);  // /T_DIM
  float dv[4], vv[4];
  #pragma unroll
  for (int nf = 0; nf < 4; nf++) {
    int col = n0 + wn * 64 + nf * 16 + lc;
    dv[nf] = dec[(size_t)b * H_DIM + col];
    vv[nf] = v[col];
  }
  float* epi = (float*)&ldsA[0][0];  // [128 rows][2 wn] floats = 1KB
  #pragma unroll
  for (int mf = 0; mf < 4; mf++) {
    #pragma unroll
    for (int r = 0; r < 4; r++) {
      float s = 0.f;
      #pragma unroll
      for (int nf = 0; nf < 4; nf++) {
        float x = acc[mf][nf][r] + dv[nf];
        x = fminf(fmaxf(x, -15.f), 15.f);
        float e = __expf(2.f * x);
        s += vv[nf] * (e - 1.f) * __builtin_amdgcn_rcpf(e + 1.f);
      }
      s += __shfl_xor(s, 1); s += __shfl_xor(s, 2);
      s += __shfl_xor(s, 4); s += __shfl_xor(s, 8);
      if (lc == 0) epi[(wm * 64 + mf * 16 + lr * 4 + r) * 2 + wn] = s;
    }
  }
  __syncthreads();
  if (tid < 128) {
    part[(m0 + tid) * 8 + bn] = epi[tid * 2] + epi[tid * 2 + 1];
  }
}

// K4: softmax over T per batch row (8 partials per row)
__global__ void softmax_kernel(const float* __restrict__ part, float* __restrict__ at) {
  int b = blockIdx.x, tid = threadIdx.x;
  __shared__ float sc[512];
  __shared__ float red[8];
  #pragma unroll
  for (int rep = 0; rep < 2; rep++) {
    int t = rep * 256 + tid;
    const float* p = part + ((size_t)b * 512 + t) * 8;
    sc[t] = p[0] + p[1] + p[2] + p[3] + p[4] + p[5] + p[6] + p[7];
  }
  __syncthreads();
  float m = fmaxf(sc[tid], sc[tid + 256]);
  for (int d = 1; d < 64; d <<= 1) m = fmaxf(m, __shfl_xor(m, d));
  if ((tid & 63) == 0) red[tid >> 6] = m;
  __syncthreads();
  m = fmaxf(fmaxf(red[0], red[1]), fmaxf(red[2], red[3]));
  float e0 = __expf(sc[tid] - m), e1 = __expf(sc[tid + 256] - m);
  float s = e0 + e1;
  for (int d = 1; d < 64; d <<= 1) s += __shfl_xor(s, d);
  if ((tid & 63) == 0) red[4 + (tid >> 6)] = s;
  __syncthreads();
  s = red[4] + red[5] + red[6] + red[7];
  float inv = 1.f / s;
  at[(size_t)b * 512 + tid] = e0 * inv;
  at[(size_t)b * 512 + tid + 256] = e1 * inv;
}

// K5: ct_d[b][h] = sum_t at[b][t]*prev_s[b][t][h]  (bf16 prev, fp32 acc)
__global__ void ctd_kernel(const unsigned short* __restrict__ pbf,
                           const float* __restrict__ at, float* __restrict__ out) {
  int blk = blockIdx.x;                 // 512 = 64 b * 8 tchunks
  int b = blk >> 3, tc = blk & 7;
  int tid = threadIdx.x;
  int h = tid * 4;
  float a0 = 0.f, a1 = 0.f, a2 = 0.f, a3 = 0.f;
  const unsigned short* base = pbf + ((size_t)b * T_DIM + (size_t)tc * 64) * H_DIM + h;
  const float* atb = at + (size_t)b * T_DIM + tc * 64;
  #pragma unroll 4
  for (int i = 0; i < 64; i++) {
    float a = atb[i];
    ushort4 u = *(const ushort4*)(base + (size_t)i * H_DIM);
    a0 += a * bf2f(u.x); a1 += a * bf2f(u.y);
    a2 += a * bf2f(u.z); a3 += a * bf2f(u.w);
  }
  atomicAdd(&out[(size_t)b * H_DIM + h + 0], a0);
  atomicAdd(&out[(size_t)b * H_DIM + h + 1], a1);
  atomicAdd(&out[(size_t)b * H_DIM + h + 2], a2);
  atomicAdd(&out[(size_t)b * H_DIM + h + 3], a3);
}

extern "C" void kernel_launch(void* const* d_in, const int* in_sizes, int n_in,
                              void* d_out, int out_size, void* d_ws, size_t ws_size,
                              hipStream_t stream) {
  (void)in_sizes; (void)n_in; (void)out_size; (void)ws_size;
  const float* s_t    = (const float*)d_in[0];
  const float* prev_s = (const float*)d_in[1];
  const float* W_prev = (const float*)d_in[2];
  const float* W_s    = (const float*)d_in[3];
  const float* b_s    = (const float*)d_in[4];
  const float* v      = (const float*)d_in[5];
  float* out = (float*)d_out;
  char* ws = (char*)d_ws;

  unsigned short* prevbf = (unsigned short*)(ws + PREVBF_OFF);
  unsigned short* wbf    = (unsigned short*)(ws + WBF_OFF);
  float* dec  = (float*)(ws + DEC_OFF);
  float* part = (float*)(ws + PART_OFF);
  float* at   = (float*)(ws + AT_OFF);

  // zero ct_d region (atomics accumulate into it)
  hipMemsetAsync(d_out, 0, (size_t)B_DIM * H_DIM * sizeof(float), stream);

  prep_kernel<<<2048, 256, 0, stream>>>(prev_s, s_t, W_prev, out, prevbf, wbf);
  dec_kernel<<<256, 256, 0, stream>>>(s_t, W_s, b_s, dec);
  score_gemm<<<2048, 256, 0, stream>>>(prevbf, wbf, dec, v, part);
  softmax_kernel<<<64, 256, 0, stream>>>(part, at);
  ctd_kernel<<<512, 256, 0, stream>>>(prevbf, at, out);
}